// Round 6
// baseline (149.827 us; speedup 1.0000x reference)
//
#include <hip/hip_runtime.h>

// GeoCyclicPadding: x (B=2, C=192, H=360, W=720) f32, p=3 -> out (B,C,366,726)
//
// BULK (98.3%): out[bc, 3+r, 3+w] = x[bc, r, w] -- thread k copies the
//   16B-ALIGNED src group x[bc,r,4k..4k+4) to out[bc,3+r,3+4k..) (store
//   misaligned by 4/12B; unavoidable since shift=12B, row stride 2904%16=8).
// EDGE (1.7%), folded into the FIRST 4347 blocks as a second job per thread
//   (all boundaries exact multiples of 256 -> block-uniform branches):
//   SEG2: middle-row edge cols, 1 thread per (row, side):
//         side0: out[.., r+3, 0..3)   = x[.., r, 717..720)
//         side1: out[.., r+3, 723..726) = x[.., r, 0..3)
//   SEG1: halo rows (ho in {0,1,2,363,364,365}), float2 groups:
//         h = 2-hr (top) / 362-hr (bottom); wr=(col+360)%726; w=(wr-3)%720
//         contiguity check w1==w0+1, scalar fallback at the 2 wrap groups/row.

typedef float f4a __attribute__((ext_vector_type(4), aligned(16)));
typedef float f4u __attribute__((ext_vector_type(4), aligned(4)));
typedef float f2u __attribute__((ext_vector_type(2), aligned(4)));

__global__ __launch_bounds__(256) void geo_pad_kernel(const float* __restrict__ x,
                                                      float* __restrict__ out) {
    constexpr int W = 720, H = 360, p = 3, Wp = 726, Hp = 366;
    constexpr unsigned SEG2 = 360u * 384u * 2u;   // 276,480  (=1080 blocks)
    constexpr unsigned SEG1 = 363u * 6u * 384u;   // 836,352  (=3267 blocks)
    constexpr unsigned EDGE = SEG2 + SEG1;        // 1,112,832 (=4347 blocks)

    const unsigned t = blockIdx.x * 256u + threadIdx.x;

    // ---- bulk: aligned-load strided copy, 16B/lane (every thread) ----
    {
        const unsigned k  = t % 180u;
        const unsigned rr = t / 180u;
        const unsigned r  = rr % 360u;
        const unsigned bc = rr / 360u;

        const f4a* src = reinterpret_cast<const f4a*>(
            x + (size_t)(bc * 360u + r) * W) + k;
        f4a v = __builtin_nontemporal_load(src);

        float* dst = out + ((size_t)bc * Hp + (r + 3)) * Wp + 3 + 4 * k;
        f4u sv; sv.x = v.x; sv.y = v.y; sv.z = v.z; sv.w = v.w;
        __builtin_nontemporal_store(sv, reinterpret_cast<f4u*>(dst));
    }

    // ---- edge jobs: only the first 4347 blocks (block-uniform) ----
    if (t < EDGE) {
        if (t < SEG2) {
            // middle-row edge columns, one thread per (row, side)
            const unsigned rowid = t >> 1;
            const int side = (int)(t & 1u);
            const unsigned bc = rowid / 360u;
            const unsigned r  = rowid % 360u;
            const float* __restrict__ srow = x + (size_t)(bc * 360u + r) * W;
            float* __restrict__ orow = out + ((size_t)bc * Hp + (r + 3)) * Wp;
            const int sbase = side ? 0 : 717;     // src cols
            const int obase = side ? 723 : 0;     // out cols
#pragma unroll
            for (int i = 0; i < 3; ++i)
                __builtin_nontemporal_store(srow[sbase + i], &orow[obase + i]);
        } else {
            // halo rows, float2 groups
            const unsigned e2 = t - SEG2;
            const unsigned g     = e2 % 363u;
            const unsigned rowid = e2 / 363u;
            const unsigned hr = rowid % 6u;
            const unsigned bc = rowid / 6u;
            const int ho = (hr < 3u) ? (int)hr : (int)(360u + hr);
            const int h  = (hr < 3u) ? (int)(2u - hr) : (int)(362u - hr);

            const float* __restrict__ srow = x + (size_t)(bc * 360u + (unsigned)h) * W;
            float* __restrict__ orow = out + ((size_t)bc * Hp + ho) * Wp;

            const int c0 = 2 * (int)g;
            int wr0 = c0 + 360;     if (wr0 >= Wp) wr0 -= Wp;
            int wr1 = c0 + 361;     if (wr1 >= Wp) wr1 -= Wp;
            int w0 = wr0 - p; if (w0 < 0) w0 += W; else if (w0 >= W) w0 -= W;
            int w1 = wr1 - p; if (w1 < 0) w1 += W; else if (w1 >= W) w1 -= W;

            f2u sv;
            if (w1 == w0 + 1) {
                sv = __builtin_nontemporal_load(
                    reinterpret_cast<const f2u*>(srow + w0));
            } else {                 // 2 groups per halo row straddle a wrap
                sv.x = srow[w0]; sv.y = srow[w1];
            }
            __builtin_nontemporal_store(sv, reinterpret_cast<f2u*>(orow + c0));
        }
    }
}

extern "C" void kernel_launch(void* const* d_in, const int* in_sizes, int n_in,
                              void* d_out, int out_size, void* d_ws, size_t ws_size,
                              hipStream_t stream) {
    const float* x = (const float*)d_in[0];
    float* out = (float*)d_out;

    // bulk threads: 384 planes * 360 rows * 180 groups = 24,883,200 = 97,200 * 256
    const unsigned total = 384u * 360u * 180u;
    geo_pad_kernel<<<total / 256u, 256, 0, stream>>>(x, out);
}